// Round 2
// baseline (208.539 us; speedup 1.0000x reference)
//
#include <hip/hip_runtime.h>
#include <math.h>

#define TT 256
#define NN 16384
#define NPAIRS (TT * NN)

__global__ __launch_bounds__(256) void collision_loss_kernel(
    const float* __restrict__ traj,     // (1, T, 2)
    const float* __restrict__ gt,       // (1, T, 3)
    const int*   __restrict__ mask,     // (1, T)
    const float* __restrict__ corners,  // (T, N, 4, 2)
    float* __restrict__ out)            // (1,)
{
    // Per-t SDC AABB (closed form: box corners are all 4 sign combos of
    // (+-W/2, +-H/2), so rotated extent is |c|*W/2 + |s|*H/2 per axis).
    __shared__ float s_axmin[TT], s_axmax[TT], s_aymin[TT], s_aymax[TT], s_m[TT];
    __shared__ float s_red[4];  // 256 threads = 4 waves

    const float HALF_W = 0.5f * (1.85f + 0.5f);   // 1.175
    const float HALF_H = 0.5f * (4.084f + 0.5f);  // 2.292

    const int tid = threadIdx.x;
    {
        const int t = tid;  // blockDim.x == TT == 256
        const float yaw = gt[t * 3 + 2];
        const float c = cosf(yaw), s = sinf(yaw);
        const float x = traj[t * 2 + 0], y = traj[t * 2 + 1];
        const float ex = fabsf(c) * HALF_W + fabsf(s) * HALF_H;
        const float ey = fabsf(s) * HALF_W + fabsf(c) * HALF_H;
        s_axmin[t] = x - ex;
        s_axmax[t] = x + ex;
        s_aymin[t] = y - ey;
        s_aymax[t] = y + ey;
        s_m[t] = (mask[t] != 0) ? 1.0f : 0.0f;
    }
    __syncthreads();

    float acc = 0.0f;
    const float4* __restrict__ c4 = (const float4*)corners;
    const int stride = gridDim.x * blockDim.x;
    for (int p = blockIdx.x * blockDim.x + tid; p < NPAIRS; p += stride) {
        const float4 v0 = c4[p * 2 + 0];  // corners 0,1: (x0,y0,x1,y1)
        const float4 v1 = c4[p * 2 + 1];  // corners 2,3: (x2,y2,x3,y3)
        const int t = p >> 14;            // p / NN (same t across wave -> LDS broadcast)

        const float bxmax = fmaxf(fmaxf(v0.x, v0.z), fmaxf(v1.x, v1.z));
        const float bxmin = fminf(fminf(v0.x, v0.z), fminf(v1.x, v1.z));
        const float bymax = fmaxf(fmaxf(v0.y, v0.w), fmaxf(v1.y, v1.w));
        const float bymin = fminf(fminf(v0.y, v0.w), fminf(v1.y, v1.w));

        const float dx = fmaxf(fminf(s_axmax[t], bxmax) - fmaxf(s_axmin[t], bxmin), 0.0f);
        const float dy = fmaxf(fminf(s_aymax[t], bymax) - fmaxf(s_aymin[t], bymin), 0.0f);
        acc += dx * dy * s_m[t];
    }

    // wave reduce (64 lanes)
    #pragma unroll
    for (int off = 32; off > 0; off >>= 1)
        acc += __shfl_down(acc, off, 64);

    const int lane = tid & 63, wid = tid >> 6;
    if (lane == 0) s_red[wid] = acc;
    __syncthreads();
    if (tid == 0) {
        const float tot = (s_red[0] + s_red[1]) + (s_red[2] + s_red[3]);
        atomicAdd(out, tot);  // WEIGHT == 1.0
    }
}

extern "C" void kernel_launch(void* const* d_in, const int* in_sizes, int n_in,
                              void* d_out, int out_size, void* d_ws, size_t ws_size,
                              hipStream_t stream) {
    const float* traj    = (const float*)d_in[0];  // sdc_traj_all
    const float* gt      = (const float*)d_in[1];  // sdc_planning_gt
    const int*   mask    = (const int*)d_in[2];    // sdc_planning_gt_mask
    const float* corners = (const float*)d_in[3];  // future_gt_corners
    float* out = (float*)d_out;

    hipMemsetAsync(out, 0, sizeof(float), stream);
    // 2048 blocks = 8 blocks/CU; each thread handles 8 (t,n) pairs.
    collision_loss_kernel<<<2048, 256, 0, stream>>>(traj, gt, mask, corners, out);
}